// Round 1
// 575.658 us; speedup vs baseline: 1.0429x; 1.0429x over previous
//
#include <hip/hip_runtime.h>
#include <hip/hip_bf16.h>

// ParallelDense: y[b,m,u] = relu(sum_f x[b,m,f] * W[m,f,u] + bias[m,u])
// B=2048, M=64, F=512, U=512.
// R4: counted-vmcnt pipeline (T4). Two raw s_barriers per iter with
// s_waitcnt vmcnt(6) between: tile kt+1's 6 global_load_lds stay in flight
// across the whole iteration instead of being drained to 0 at __syncthreads.
// wt_prep rewritten: 64x64 tile, float4 global loads, LDS transpose,
// 16B/lane global stores (was scalar 2B stores).

typedef __attribute__((ext_vector_type(8))) short bf16x8;
typedef __attribute__((ext_vector_type(4))) float f32x4;

#define LDS_S 40   // (fallback kernel only)

__device__ __forceinline__ unsigned pk_bf16(float a, float b) {
    float2 t; t.x = a; t.y = b;
    __hip_bfloat162 h = __float22bfloat162_rn(t);   // v_cvt_pk_bf16_f32 (RNE)
    union { __hip_bfloat162 h; unsigned u; } cv;
    cv.h = h;
    return cv.u;
}

__device__ __forceinline__ void gld16(const void* g, void* l) {
    __builtin_amdgcn_global_load_lds(
        (const __attribute__((address_space(1))) void*)g,
        (__attribute__((address_space(3))) void*)l, 16, 0, 0);
}

// ---------------- prep: W[m][f][u] fp32 -> Wt[m][u][f] bf16 ----------------
// 64x64 tile per block. Global loads: float4 (256B/row segments).
// LDS transposed scatter (scalar b16 writes, cheap), vector b128 reads,
// 16B/lane global stores. Grid (8,8,64) x 256 threads.
__global__ void wt_prep_kernel(const float* __restrict__ W, short* __restrict__ Wt) {
    __shared__ short t[64][80];     // stride 160B (16B-aligned rows), 10KB
    const int m   = blockIdx.z;
    const int f0  = blockIdx.y * 64;
    const int u0  = blockIdx.x * 64;
    const int tid = threadIdx.x;    // 0..255
    const int fl  = tid >> 4;       // 0..15
    const int us  = tid & 15;       // 16B slot (4 u-values)
    #pragma unroll
    for (int i = 0; i < 4; ++i) {
        const int f = fl + 16 * i;
        float4 v = *(const float4*)(W + ((size_t)m * 512 + f0 + f) * 512 + u0 + us * 4);
        t[us * 4 + 0][f] = (short)(pk_bf16(v.x, v.x) & 0xffff);
        t[us * 4 + 1][f] = (short)(pk_bf16(v.y, v.y) & 0xffff);
        t[us * 4 + 2][f] = (short)(pk_bf16(v.z, v.z) & 0xffff);
        t[us * 4 + 3][f] = (short)(pk_bf16(v.w, v.w) & 0xffff);
    }
    __syncthreads();
    const int ur = tid >> 3;        // 0..31
    const int fs = tid & 7;         // 16B slot within f-row
    #pragma unroll
    for (int i = 0; i < 2; ++i) {
        const int u = ur + 32 * i;
        *(uint4*)(Wt + ((size_t)m * 512 + u0 + u) * 512 + f0 + fs * 8) =
            *(const uint4*)&t[u][fs * 8];
    }
}

// ---------------- main GEMM ----------------
// LDS layouts (unpadded, required by global_load_lds; XOR-swizzled for banks):
//   A: fp32, row r (128 rows) = 32 floats = 8 chunks of 16B; chunk c stored at
//      position c ^ (r&7).  B: bf16, 4 chunks of 16B at pos c ^ ((r>>1)&3).
// Pipeline per iter:
//   s_barrier            (all waves done reading buf p^1)
//   issue 6 DMAs -> p^1  (tile kt+1)
//   s_waitcnt vmcnt(6)   (tile kt landed; kt+1 stays in flight)
//   s_barrier            (everyone's tile kt landed)
//   ds_read frags + cvt + 16 MFMA on buf p
__global__ __launch_bounds__(256, 3) void pdense_main(const float* __restrict__ X,
                                                      const short* __restrict__ Wt,
                                                      const float* __restrict__ bias,
                                                      float* __restrict__ Out) {
    __shared__ float ldsA[2][128 * 32];   // 16 KB each
    __shared__ short ldsB[2][128 * 32];   //  8 KB each   (total 48 KB)

    const int tid  = threadIdx.x;
    const int lane = tid & 63;
    const int wave = tid >> 6;
    const int q    = lane >> 4;           // quad -> k-offset q*8
    const int ln   = lane & 15;
    const int wr   = (wave >> 1) * 64;
    const int wc   = (wave & 1) * 64;

    // XCD swizzle: id&7 = XCD (round-robin dispatch); each XCD owns 8 masks;
    // within an XCD, consecutive slots = 4 ut-blocks sharing the same x rows.
    const int id   = blockIdx.x;
    const int xcd  = id & 7;
    const int slot = id >> 3;
    const int m    = xcd * 8 + (slot >> 6);
    const int rem  = slot & 63;
    const int bt   = rem >> 2;
    const int ut   = rem & 3;
    const int row0 = bt * 128;
    const int col0 = ut * 128;

    // ---- DMA source addresses ----
    const int arow = wave * 32 + (lane >> 3);
    const int ac   = (lane & 7) ^ (lane >> 3);
    const float* agp = X + (size_t)(row0 + arow) * 32768 + m * 512 + ac * 4;
    const int brow = wave * 32 + (lane >> 2);
    const int bc   = (lane & 3) ^ ((lane >> 3) & 3);
    const short* bgp = Wt + (size_t)m * 262144 + (size_t)(col0 + brow) * 512 + bc * 8;

    f32x4 acc[4][4];
    #pragma unroll
    for (int i = 0; i < 4; ++i)
        #pragma unroll
        for (int j = 0; j < 4; ++j)
            acc[i][j] = (f32x4)0.0f;

    // prologue: DMA tile 0 into buffer 0
    #pragma unroll
    for (int i = 0; i < 4; ++i)
        gld16(agp + (size_t)i * 8 * 32768, &ldsA[0][(wave * 32 + i * 8) * 32]);
    #pragma unroll
    for (int j = 0; j < 2; ++j)
        gld16(bgp + (size_t)j * 16 * 512, &ldsB[0][(wave * 32 + j * 16) * 32]);

    const int s1 = (ln >> 1) & 3;
    const int s0 = ln & 1;

    for (int kt = 0; kt < 16; ++kt) {
        const int p = kt & 1;

        // BARRIER A: all waves finished reading buf p^1 (frags of tile kt-1
        // were consumed by MFMA before this point in each wave's program order)
        __builtin_amdgcn_sched_barrier(0);
        __builtin_amdgcn_s_barrier();
        __builtin_amdgcn_sched_barrier(0);

        // issue tile kt+1 into buf p^1; wait only for tile kt (vmcnt 6)
        if (kt + 1 < 16) {
            const int ko = (kt + 1) * 32;
            #pragma unroll
            for (int i = 0; i < 4; ++i)
                gld16(agp + ko + (size_t)i * 8 * 32768, &ldsA[p ^ 1][(wave * 32 + i * 8) * 32]);
            #pragma unroll
            for (int j = 0; j < 2; ++j)
                gld16(bgp + ko + (size_t)j * 16 * 512, &ldsB[p ^ 1][(wave * 32 + j * 16) * 32]);
            __builtin_amdgcn_sched_barrier(0);
            asm volatile("s_waitcnt vmcnt(6)" ::: "memory");
        } else {
            asm volatile("s_waitcnt vmcnt(0)" ::: "memory");
        }
        __builtin_amdgcn_sched_barrier(0);

        // BARRIER B: everyone's tile kt has landed in buf p
        __builtin_amdgcn_s_barrier();
        __builtin_amdgcn_sched_barrier(0);

        // ---- fragments (swizzled reads) + cvt + MFMA on buf p ----
        bf16x8 aF[4], bF[4];
        #pragma unroll
        for (int i = 0; i < 4; ++i) {
            const int r = wr + i * 16 + ln;
            const float* base = &ldsA[p][r * 32 + ((q ^ s1) << 3)];
            float4 ca = *(const float4*)(base + (s0 << 2));        // k = q*8 .. +3
            float4 cb = *(const float4*)(base + ((1 - s0) << 2));  // k = q*8+4 .. +7
            union { bf16x8 v; uint4 u; } fr;
            fr.u.x = pk_bf16(ca.x, ca.y);
            fr.u.y = pk_bf16(ca.z, ca.w);
            fr.u.z = pk_bf16(cb.x, cb.y);
            fr.u.w = pk_bf16(cb.z, cb.w);
            aF[i] = fr.v;
        }
        #pragma unroll
        for (int j = 0; j < 4; ++j) {
            const int r = wc + j * 16 + ln;
            bF[j] = *(const bf16x8*)&ldsB[p][r * 32 + ((q ^ s1) << 3)];
        }
        #pragma unroll
        for (int i = 0; i < 4; ++i)
            #pragma unroll
            for (int j = 0; j < 4; ++j)
                acc[i][j] = __builtin_amdgcn_mfma_f32_16x16x32_bf16(aF[i], bF[j], acc[i][j], 0, 0, 0);
    }

    // epilogue: bias + relu + store. D map: col = lane&15, row = quad*4 + reg
    #pragma unroll
    for (int j = 0; j < 4; ++j) {
        const int c = col0 + wc + j * 16 + ln;
        const float bv = bias[m * 512 + c];
        #pragma unroll
        for (int i = 0; i < 4; ++i) {
            const int r = row0 + wr + i * 16 + q * 4;
            float* op = Out + (size_t)r * 32768 + m * 512 + c;
            f32x4 v = acc[i][j];
            #pragma unroll
            for (int t = 0; t < 4; ++t) {
                float val = v[t] + bv;
                op[(size_t)t * 32768] = val > 0.0f ? val : 0.0f;
            }
        }
    }
}

// ---------------- fallback (R1 kernel, used if ws too small) ----------------
__global__ void pdense_fallback(const float* __restrict__ X,
                                const float* __restrict__ Wp,
                                const float* __restrict__ bias,
                                float* __restrict__ Out) {
    __shared__ short ldsA[128 * LDS_S];
    __shared__ short ldsB[128 * LDS_S];

    const int tid  = threadIdx.x;
    const int lane = tid & 63;
    const int wave = tid >> 6;
    const int q    = lane >> 4;
    const int ln   = lane & 15;
    const int wr   = (wave >> 1) * 64;
    const int wc   = (wave & 1) * 64;

    const int m    = blockIdx.y;
    const int bt   = blockIdx.x & 15;
    const int ut   = blockIdx.x >> 4;
    const int row0 = bt * 128;
    const int col0 = ut * 128;

    const int ar0 = tid >> 2;
    const int ak0 = (tid & 3) * 8;
    const int ar1 = ar0 + 64;
    const float* aP0 = X + (size_t)(row0 + ar0) * 32768 + m * 512 + ak0;
    const float* aP1 = X + (size_t)(row0 + ar1) * 32768 + m * 512 + ak0;

    const int k0 = (tid & 7) * 4;
    const int u0 = (tid >> 3) * 4;
    const float* bP = Wp + (size_t)m * 262144 + (size_t)k0 * 512 + col0 + u0;

    f32x4 acc[4][4];
    #pragma unroll
    for (int i = 0; i < 4; ++i)
        #pragma unroll
        for (int j = 0; j < 4; ++j)
            acc[i][j] = (f32x4)0.0f;

    float4 a_pre[2][2];
    float4 b_pre[4];

    a_pre[0][0] = ((const float4*)aP0)[0];
    a_pre[0][1] = ((const float4*)aP0)[1];
    a_pre[1][0] = ((const float4*)aP1)[0];
    a_pre[1][1] = ((const float4*)aP1)[1];
    #pragma unroll
    for (int i = 0; i < 4; ++i)
        b_pre[i] = *(const float4*)(bP + (size_t)i * 512);

    for (int kt = 0; kt < 16; ++kt) {
        {
            uint4 w0, w1;
            w0.x = pk_bf16(a_pre[0][0].x, a_pre[0][0].y);
            w0.y = pk_bf16(a_pre[0][0].z, a_pre[0][0].w);
            w0.z = pk_bf16(a_pre[0][1].x, a_pre[0][1].y);
            w0.w = pk_bf16(a_pre[0][1].z, a_pre[0][1].w);
            *(uint4*)&ldsA[ar0 * LDS_S + ak0] = w0;
            w1.x = pk_bf16(a_pre[1][0].x, a_pre[1][0].y);
            w1.y = pk_bf16(a_pre[1][0].z, a_pre[1][0].w);
            w1.z = pk_bf16(a_pre[1][1].x, a_pre[1][1].y);
            w1.w = pk_bf16(a_pre[1][1].z, a_pre[1][1].w);
            *(uint4*)&ldsA[ar1 * LDS_S + ak0] = w1;
            #pragma unroll
            for (int j = 0; j < 4; ++j) {
                float c0 = ((const float*)&b_pre[0])[j];
                float c1 = ((const float*)&b_pre[1])[j];
                float c2 = ((const float*)&b_pre[2])[j];
                float c3 = ((const float*)&b_pre[3])[j];
                uint2 wv;
                wv.x = pk_bf16(c0, c1);
                wv.y = pk_bf16(c2, c3);
                *(uint2*)&ldsB[(u0 + j) * LDS_S + k0] = wv;
            }
        }
        __syncthreads();

        if (kt + 1 < 16) {
            const int ko = (kt + 1) * 32;
            a_pre[0][0] = ((const float4*)(aP0 + ko))[0];
            a_pre[0][1] = ((const float4*)(aP0 + ko))[1];
            a_pre[1][0] = ((const float4*)(aP1 + ko))[0];
            a_pre[1][1] = ((const float4*)(aP1 + ko))[1];
            #pragma unroll
            for (int i = 0; i < 4; ++i)
                b_pre[i] = *(const float4*)(bP + (size_t)(ko + i) * 512);
        }

        bf16x8 aF[4], bF[4];
        #pragma unroll
        for (int i = 0; i < 4; ++i)
            aF[i] = *(const bf16x8*)&ldsA[(wr + i * 16 + ln) * LDS_S + q * 8];
        #pragma unroll
        for (int j = 0; j < 4; ++j)
            bF[j] = *(const bf16x8*)&ldsB[(wc + j * 16 + ln) * LDS_S + q * 8];
        #pragma unroll
        for (int i = 0; i < 4; ++i)
            #pragma unroll
            for (int j = 0; j < 4; ++j)
                acc[i][j] = __builtin_amdgcn_mfma_f32_16x16x32_bf16(aF[i], bF[j], acc[i][j], 0, 0, 0);

        __syncthreads();
    }

    #pragma unroll
    for (int j = 0; j < 4; ++j) {
        const int c = col0 + wc + j * 16 + ln;
        const float bv = bias[m * 512 + c];
        #pragma unroll
        for (int i = 0; i < 4; ++i) {
            const int r = row0 + wr + i * 16 + q * 4;
            float* op = Out + (size_t)r * 32768 + m * 512 + c;
            f32x4 v = acc[i][j];
            #pragma unroll
            for (int t = 0; t < 4; ++t) {
                float val = v[t] + bv;
                op[(size_t)t * 32768] = val > 0.0f ? val : 0.0f;
            }
        }
    }
}

extern "C" void kernel_launch(void* const* d_in, const int* in_sizes, int n_in,
                              void* d_out, int out_size, void* d_ws, size_t ws_size,
                              hipStream_t stream) {
    const float* x    = (const float*)d_in[0];   // [2048, 64, 512]
    const float* W    = (const float*)d_in[1];   // [64, 512, 512]
    const float* bias = (const float*)d_in[2];   // [64, 512]
    float* out = (float*)d_out;                  // [2048, 64*512]

    const size_t wt_bytes = (size_t)64 * 512 * 512 * sizeof(short);  // 33.55 MB
    if (ws_size >= wt_bytes) {
        short* Wt = (short*)d_ws;
        hipLaunchKernelGGL(wt_prep_kernel, dim3(8, 8, 64), dim3(256), 0, stream, W, Wt);
        hipLaunchKernelGGL(pdense_main, dim3(4096), dim3(256), 0, stream, x, Wt, bias, out);
    } else {
        hipLaunchKernelGGL(pdense_fallback, dim3(64, 64), dim3(256), 0, stream, x, W, bias, out);
    }
}